// Round 9
// baseline (266.678 us; speedup 1.0000x reference)
//
#include <hip/hip_runtime.h>
#include <math.h>

#define BATCH 8
#define NN 2048
#define FIN 256
#define FOUT 64
#define ALPHA 0.2f

typedef __attribute__((ext_vector_type(8))) short bf16x8;
typedef __attribute__((ext_vector_type(4))) float f32x4;

#define NWORD64 524288u   // adj ints / 64 = 33,554,432 / 64
#define STREAMW 7168u     // 1792 streaming blocks * 4 waves

static __device__ __forceinline__ unsigned short f2bf(float f) {
  unsigned int u = __float_as_uint(f);
  u += 0x7fffu + ((u >> 16) & 1u);
  return (unsigned short)(u >> 16);
}
static __device__ __forceinline__ float bf2f(unsigned short h) {
  return __uint_as_float(((unsigned int)h) << 16);
}

// ---------------------------------------------------------------------------
// K1f: fused. Blocks 0..255: h = x@W via MFMA (hi/lo bf16 split), el/er,
// pre-swizzled h image (IDENTICAL to prior rounds). Blocks 256..2047: stream
// adj -> 1-bit mask (4MB) via coalesced dword loads + __ballot, 16-deep
// load batches so ~16 x 256B stay in flight per wave (pure BW streaming).
// ---------------------------------------------------------------------------
__global__ __launch_bounds__(256) void k1_fused(
    const float* __restrict__ x, const int* __restrict__ adj,
    const float* __restrict__ W, const float* __restrict__ a,
    float* __restrict__ el, float* __restrict__ er,
    unsigned char* __restrict__ hS, unsigned long long* __restrict__ bm64) {
  __shared__ __align__(16) unsigned short lds[32768];  // 64 KB
  const int bid = blockIdx.x;
  const int t = threadIdx.x;
  const int wv = t >> 6;
  const int l = t & 63;

  if (bid >= 256) {
    // ---- streaming role: adj -> bitmask ----
    const unsigned int wslot = (unsigned int)(bid - 256) * 4u + (unsigned int)wv;
    for (unsigned int base = wslot; base < NWORD64; base += 16u * STREAMW) {
      int v[16];
      unsigned int gg[16];
      #pragma unroll
      for (int k = 0; k < 16; ++k) {
        gg[k] = base + (unsigned int)k * STREAMW;
        v[k] = (gg[k] < NWORD64) ? adj[(size_t)gg[k] * 64 + l] : 0;
      }
      #pragma unroll
      for (int k = 0; k < 16; ++k) {
        if (gg[k] < NWORD64) {
          unsigned long long m = __ballot(v[k] > 0);
          if (l == 0) bm64[gg[k]] = m;
        }
      }
    }
    return;
  }

  // ---- h role (unchanged numerics) ----
  const int l15 = l & 15;
  const int kg = l >> 4;

  // phase 0: stage W as bf16 hi/lo planes, XOR-swizzled:
  // u16 idx = plane*16384 + o*256 + ((k>>3)^(o&7))*8 + (k&7)
  {
    const float4* W4 = (const float4*)W;
    #pragma unroll
    for (int i = 0; i < 16; ++i) {
      int f = t + i * 256;            // float4 index, 0..4095
      float4 v = W4[f];
      int k = f >> 4;                 // W row 0..255
      int ob = (f & 15) * 4;
      float vv[4] = {v.x, v.y, v.z, v.w};
      #pragma unroll
      for (int c = 0; c < 4; ++c) {
        int o = ob + c;
        unsigned short hi = f2bf(vv[c]);
        unsigned short lo = f2bf(vv[c] - bf2f(hi));
        int idx = o * 256 + (((k >> 3) ^ (o & 7)) * 8) + (k & 7);
        lds[idx] = hi;
        lds[16384 + idx] = lo;
      }
    }
  }
  __syncthreads();

  const int row = bid * 64 + wv * 16 + l15;
  f32x4 acc[4] = {{0.f,0.f,0.f,0.f},{0.f,0.f,0.f,0.f},
                  {0.f,0.f,0.f,0.f},{0.f,0.f,0.f,0.f}};
  const float* xrow = x + (size_t)row * FIN;

  #pragma unroll
  for (int ks = 0; ks < 8; ++ks) {
    int k0 = ks * 32;
    float4 xa = *(const float4*)(xrow + k0 + kg * 8);
    float4 xb = *(const float4*)(xrow + k0 + kg * 8 + 4);
    float xv[8] = {xa.x, xa.y, xa.z, xa.w, xb.x, xb.y, xb.z, xb.w};
    bf16x8 ahi, alo;
    #pragma unroll
    for (int j = 0; j < 8; ++j) {
      unsigned short hi = f2bf(xv[j]);
      unsigned short lo = f2bf(xv[j] - bf2f(hi));
      ahi[j] = (short)hi;
      alo[j] = (short)lo;
    }
    int kgidx = ks * 4 + kg;
    #pragma unroll
    for (int ot = 0; ot < 4; ++ot) {
      int o = ot * 16 + l15;
      int base = o * 256 + ((kgidx ^ (o & 7)) * 8);
      bf16x8 bhi = *(const bf16x8*)&lds[base];
      bf16x8 blo = *(const bf16x8*)&lds[16384 + base];
      acc[ot] = __builtin_amdgcn_mfma_f32_16x16x32_bf16(ahi, bhi, acc[ot], 0, 0, 0);
      acc[ot] = __builtin_amdgcn_mfma_f32_16x16x32_bf16(ahi, blo, acc[ot], 0, 0, 0);
      acc[ot] = __builtin_amdgcn_mfma_f32_16x16x32_bf16(alo, bhi, acc[ot], 0, 0, 0);
    }
  }

  // el/er: reduce across the 16 col-lanes (same kg group)
  float aLv[4], aRv[4];
  #pragma unroll
  for (int ot = 0; ot < 4; ++ot) {
    aLv[ot] = a[ot * 16 + l15];
    aRv[ot] = a[64 + ot * 16 + l15];
  }
  #pragma unroll
  for (int jj = 0; jj < 4; ++jj) {
    float pl = 0.f, pr = 0.f;
    #pragma unroll
    for (int ot = 0; ot < 4; ++ot) {
      pl += acc[ot][jj] * aLv[ot];
      pr += acc[ot][jj] * aRv[ot];
    }
    #pragma unroll
    for (int s = 1; s < 16; s <<= 1) {
      pl += __shfl_xor(pl, s);
      pr += __shfl_xor(pr, s);
    }
    if (l15 == 0) {
      int grow = bid * 64 + wv * 16 + kg * 4 + jj;
      el[grow] = pl;
      er[grow] = pr;
    }
  }

  // phase 2: hi/lo split of h, scatter into the image layout (alias lds):
  // u16 idx = ((ks2*2+plane)*64 + o)*32 + (kg2 ^ ((o>>1)&3))*8 + j
  __syncthreads();
  #pragma unroll
  for (int ot = 0; ot < 4; ++ot) {
    int o = ot * 16 + l15;
    int xorv = (o >> 1) & 3;
    #pragma unroll
    for (int jj = 0; jj < 4; ++jj) {
      int m_loc = wv * 16 + kg * 4 + jj;
      int ks2 = m_loc >> 5;
      int kg2 = (m_loc >> 3) & 3;
      int j = m_loc & 7;
      int kgp = kg2 ^ xorv;
      float v = acc[ot][jj];
      unsigned short hi = f2bf(v);
      unsigned short lo = f2bf(v - bf2f(hi));
      int base = ((ks2 * 2 + 0) * 64 + o) * 32 + kgp * 8 + j;
      lds[base] = hi;
      lds[base + 2048] = lo;  // plane stride = 64*32 u16
    }
  }
  __syncthreads();

  // dump 16KB image contiguously to global
  {
    const uint4* src = (const uint4*)(const void*)lds;
    uint4* dst = (uint4*)(hS + (size_t)bid * 16384);
    #pragma unroll
    for (int i = 0; i < 4; ++i) dst[t + i * 256] = src[t + i * 256];
  }
}

// ---------------------------------------------------------------------------
// K2: masked-softmax attention as MFMA GEMM — bitmask edition (R7 structure).
// 512 blocks x 256 thr; block owns 32 n-rows, wave wv owns m-window
// [wv*512,(wv+1)*512) = 16 chunks of 32 m. Per chunk per row-tile the mask is
// ONE u32 (broadcast across kg lanes, L2/L3-resident 4MB total) — the HBM
// adj gather is GONE. B-frags (h hi/lo) load straight from the L2-resident
// pre-swizzled image at chunk start (consumed after the j-loop -> latency
// covered). No barriers/asm in the main loop. LDS = end combine only.
// ---------------------------------------------------------------------------
__global__ __launch_bounds__(256, 2) void k2_attn(
    const unsigned int* __restrict__ bmw, const unsigned char* __restrict__ hS,
    const float* __restrict__ el, const float* __restrict__ er,
    float* __restrict__ out) {
  __shared__ __align__(16) float cb[3 * 64 * 36];  // 27.6 KB combine buffer
  const int t = threadIdx.x;
  const int wv = t >> 6;
  const int l = t & 63;
  const int l15 = l & 15;
  const int kg = l >> 4;

  // XCD-bijective swizzle: 512 blocks, 64/XCD -> each XCD sees one batch
  int bid = blockIdx.x;
  int swz = (bid & 7) * 64 + (bid >> 3);
  int b = swz >> 6;
  int n0 = (swz & 63) * 32;

  const int row0 = n0 + l15;        // rt=0 rows
  const int row1 = n0 + 16 + l15;   // rt=1 rows
  const float eL0 = el[b * NN + row0];
  const float eL1 = el[b * NN + row1];
  const unsigned int* bmr0 = bmw + ((size_t)(b * NN + row0)) * 64 + wv * 16;
  const unsigned int* bmr1 = bmw + ((size_t)(b * NN + row1)) * 64 + wv * 16;
  const float* erp = er + b * NN + wv * 512;
  const unsigned char* hW = hS + (size_t)b * 32 * 16384 + (size_t)wv * 16 * 8192;
  const int laneoff = l15 * 64 + ((kg ^ ((l >> 1) & 3)) * 16);
  const int shift = kg * 8;

  f32x4 acc[2][4] = {{{0.f,0.f,0.f,0.f},{0.f,0.f,0.f,0.f},
                      {0.f,0.f,0.f,0.f},{0.f,0.f,0.f,0.f}},
                     {{0.f,0.f,0.f,0.f},{0.f,0.f,0.f,0.f},
                      {0.f,0.f,0.f,0.f},{0.f,0.f,0.f,0.f}}};
  float S0 = 0.f, S1 = 0.f;

  // prologue: mask words + er for chunk 0
  unsigned int w0c = bmr0[0], w1c = bmr1[0];
  float4 evc0 = *(const float4*)(erp + kg * 8);
  float4 evc1 = *(const float4*)(erp + kg * 8 + 4);

  #pragma unroll
  for (int c = 0; c < 16; ++c) {
    // B-fragments straight from L2 (consumed after j-loop)
    bf16x8 curH[4], curL[4];
    {
      const unsigned char* p_ = hW + (size_t)c * 8192 + laneoff;
      #pragma unroll
      for (int ot = 0; ot < 4; ++ot) {
        curH[ot] = *(const bf16x8*)(p_ + ot * 1024);
        curL[ot] = *(const bf16x8*)(p_ + ot * 1024 + 4096);
      }
    }
    unsigned int w0n, w1n;
    float4 evn0, evn1;
    if (c < 15) {
      w0n = bmr0[c + 1];
      w1n = bmr1[c + 1];
      evn0 = *(const float4*)(erp + (c + 1) * 32 + kg * 8);
      evn1 = *(const float4*)(erp + (c + 1) * 32 + kg * 8 + 4);
    }

    float ee[8] = {evc0.x, evc0.y, evc0.z, evc0.w,
                   evc1.x, evc1.y, evc1.z, evc1.w};

    bf16x8 af0h, af0l, af1h, af1l;
    #pragma unroll
    for (int j = 0; j < 8; ++j) {
      float e0 = eL0 + ee[j];
      e0 = fmaxf(e0, ALPHA * e0);
      float w0 = ((w0c >> (shift + j)) & 1u) ? __expf(e0) : 0.f;
      unsigned short h0 = f2bf(w0);
      float w0h = bf2f(h0);
      unsigned short l0 = f2bf(w0 - w0h);
      af0h[j] = (short)h0;
      af0l[j] = (short)l0;
      S0 += w0h + bf2f(l0);               // denom == effective numer weight

      float e1 = eL1 + ee[j];
      e1 = fmaxf(e1, ALPHA * e1);
      float w1 = ((w1c >> (shift + j)) & 1u) ? __expf(e1) : 0.f;
      unsigned short h1 = f2bf(w1);
      float w1h = bf2f(h1);
      unsigned short l1 = f2bf(w1 - w1h);
      af1h[j] = (short)h1;
      af1l[j] = (short)l1;
      S1 += w1h + bf2f(l1);
    }

    #pragma unroll
    for (int ot = 0; ot < 4; ++ot) {
      acc[0][ot] = __builtin_amdgcn_mfma_f32_16x16x32_bf16(af0h, curH[ot], acc[0][ot], 0, 0, 0);
      acc[0][ot] = __builtin_amdgcn_mfma_f32_16x16x32_bf16(af0h, curL[ot], acc[0][ot], 0, 0, 0);
      acc[0][ot] = __builtin_amdgcn_mfma_f32_16x16x32_bf16(af0l, curH[ot], acc[0][ot], 0, 0, 0);
      acc[1][ot] = __builtin_amdgcn_mfma_f32_16x16x32_bf16(af1h, curH[ot], acc[1][ot], 0, 0, 0);
      acc[1][ot] = __builtin_amdgcn_mfma_f32_16x16x32_bf16(af1h, curL[ot], acc[1][ot], 0, 0, 0);
      acc[1][ot] = __builtin_amdgcn_mfma_f32_16x16x32_bf16(af1l, curH[ot], acc[1][ot], 0, 0, 0);
    }

    if (c < 15) { w0c = w0n; w1c = w1n; evc0 = evn0; evc1 = evn1; }
  }

  // per-wave S reduce across kg groups (replicates row-l15 denom to all lanes)
  S0 += __shfl_xor(S0, 16); S0 += __shfl_xor(S0, 32);
  S1 += __shfl_xor(S1, 16); S1 += __shfl_xor(S1, 32);

  // cross-wave combine of m-window partials: waves 1..3 publish, wave 0 sums
  __syncthreads();
  if (wv > 0) {
    float* dst = cb + ((wv - 1) * 64 + l) * 36;
    #pragma unroll
    for (int ot = 0; ot < 4; ++ot) {
      *(f32x4*)(dst + ot * 4)      = acc[0][ot];
      *(f32x4*)(dst + 16 + ot * 4) = acc[1][ot];
    }
    dst[32] = S0;
    dst[33] = S1;
  }
  __syncthreads();
  if (wv != 0) return;

  #pragma unroll
  for (int p = 0; p < 3; ++p) {
    const float* src = cb + (p * 64 + l) * 36;
    #pragma unroll
    for (int ot = 0; ot < 4; ++ot) {
      acc[0][ot] += *(const f32x4*)(src + ot * 4);
      acc[1][ot] += *(const f32x4*)(src + 16 + ot * 4);
    }
    S0 += src[32];
    S1 += src[33];
  }

  float Sj0[4], Sj1[4];
  #pragma unroll
  for (int jj = 0; jj < 4; ++jj) {
    Sj0[jj] = __shfl(S0, kg * 4 + jj);
    Sj1[jj] = __shfl(S1, kg * 4 + jj);
  }
  #pragma unroll
  for (int ot = 0; ot < 4; ++ot) {
    #pragma unroll
    for (int jj = 0; jj < 4; ++jj) {
      float v0 = acc[0][ot][jj] / Sj0[jj];
      float r0 = v0 > 0.f ? v0 : expm1f(v0);
      out[((size_t)b * NN + n0 + kg * 4 + jj) * FOUT + ot * 16 + l15] = r0;
      float v1 = acc[1][ot][jj] / Sj1[jj];
      float r1 = v1 > 0.f ? v1 : expm1f(v1);
      out[((size_t)b * NN + n0 + 16 + kg * 4 + jj) * FOUT + ot * 16 + l15] = r1;
    }
  }
}

extern "C" void kernel_launch(void* const* d_in, const int* in_sizes, int n_in,
                              void* d_out, int out_size, void* d_ws, size_t ws_size,
                              hipStream_t stream) {
  const float* x   = (const float*)d_in[0];
  const int*   adj = (const int*)d_in[1];
  const float* W   = (const float*)d_in[2];
  const float* a   = (const float*)d_in[3];
  float* out = (float*)d_out;

  // ws layout: hS images (4MB) | el (64KB) | er (64KB) | bitmask (4MB)
  unsigned char* hS = (unsigned char*)d_ws;
  float* el = (float*)(hS + (size_t)BATCH * 32 * 16384);
  float* er = el + BATCH * NN;
  unsigned long long* bm64 = (unsigned long long*)(er + BATCH * NN);

  hipLaunchKernelGGL(k1_fused, dim3(2048), dim3(256), 0, stream,
                     x, adj, W, a, el, er, hS, bm64);
  hipLaunchKernelGGL(k2_attn, dim3(512), dim3(256), 0, stream,
                     (const unsigned int*)bm64, hS, el, er, out);
}

// Round 10
// 165.010 us; speedup vs baseline: 1.6161x; 1.6161x over previous
//
#include <hip/hip_runtime.h>
#include <math.h>

#define BATCH 8
#define NN 2048
#define FIN 256
#define FOUT 64
#define ALPHA 0.2f

typedef __attribute__((ext_vector_type(8))) short bf16x8;
typedef __attribute__((ext_vector_type(4))) float f32x4;

static __device__ __forceinline__ unsigned short f2bf(float f) {
  unsigned int u = __float_as_uint(f);
  u += 0x7fffu + ((u >> 16) & 1u);
  return (unsigned short)(u >> 16);
}
static __device__ __forceinline__ float bf2f(unsigned short h) {
  return __uint_as_float(((unsigned int)h) << 16);
}

// ---------------------------------------------------------------------------
// K1f: fused. Blocks 0..255: h = x@W via MFMA (hi/lo bf16 split), el/er,
// pre-swizzled h image (IDENTICAL numerics to prior rounds).
// Blocks 256..2303 (8192 waves): adj -> 1-bit mask (4MB). Each wave: exactly
// 16 int4 loads (1KB each, coalesced, no guards) issued back-to-back, then
// sched_barrier(0) so the pack loop CANNOT fuse into the load stream (the
// round-9 failure: per-element vmcnt(0) serialization). Pack: per-lane
// 4-bit nibble -> 3-step shfl_xor butterfly -> natural-bit-order u32 per
// 8-lane group. One latency exposure per wave, then pure BW.
// ---------------------------------------------------------------------------
__global__ __launch_bounds__(256) void k1_fused(
    const float* __restrict__ x, const int* __restrict__ adj,
    const float* __restrict__ W, const float* __restrict__ a,
    float* __restrict__ el, float* __restrict__ er,
    unsigned char* __restrict__ hS, unsigned int* __restrict__ bm32) {
  __shared__ __align__(16) unsigned short lds[32768];  // 64 KB
  const int bid = blockIdx.x;
  const int t = threadIdx.x;
  const int wv = t >> 6;
  const int l = t & 63;

  if (bid >= 256) {
    // ---- streaming role: adj -> bitmask ----
    const unsigned int wslot = (unsigned int)(bid - 256) * 4u + (unsigned int)wv;
    const int4* adj4 = (const int4*)adj;
    int4 v[16];
    #pragma unroll
    for (int i = 0; i < 16; ++i) {
      unsigned int f = wslot + (unsigned int)i * 8192u;  // f < 131072 exact
      v[i] = adj4[(size_t)f * 64 + l];
    }
    __builtin_amdgcn_sched_barrier(0);   // loads stay issued; pack follows
    #pragma unroll
    for (int i = 0; i < 16; ++i) {
      unsigned int f = wslot + (unsigned int)i * 8192u;
      int nib = (v[i].x > 0 ? 1 : 0) | (v[i].y > 0 ? 2 : 0) |
                (v[i].z > 0 ? 4 : 0) | (v[i].w > 0 ? 8 : 0);
      int o = __shfl_xor(nib, 1);
      int byt = (l & 1) ? (o | (nib << 4)) : (nib | (o << 4));
      o = __shfl_xor(byt, 2);
      int h16 = (l & 2) ? (o | (byt << 8)) : (byt | (o << 8));
      o = __shfl_xor(h16, 4);
      unsigned int w32 = (l & 4) ? ((unsigned int)o | ((unsigned int)h16 << 16))
                                 : ((unsigned int)h16 | ((unsigned int)o << 16));
      if ((l & 7) == 0) {
        unsigned int row = f >> 3;                   // 8 f-blocks per row
        bm32[(size_t)row * 64 + (f & 7) * 8 + (l >> 3)] = w32;
      }
    }
    return;
  }

  // ---- h role (unchanged numerics) ----
  const int l15 = l & 15;
  const int kg = l >> 4;

  // phase 0: stage W as bf16 hi/lo planes, XOR-swizzled:
  // u16 idx = plane*16384 + o*256 + ((k>>3)^(o&7))*8 + (k&7)
  {
    const float4* W4 = (const float4*)W;
    #pragma unroll
    for (int i = 0; i < 16; ++i) {
      int f = t + i * 256;            // float4 index, 0..4095
      float4 v = W4[f];
      int k = f >> 4;                 // W row 0..255
      int ob = (f & 15) * 4;
      float vv[4] = {v.x, v.y, v.z, v.w};
      #pragma unroll
      for (int c = 0; c < 4; ++c) {
        int o = ob + c;
        unsigned short hi = f2bf(vv[c]);
        unsigned short lo = f2bf(vv[c] - bf2f(hi));
        int idx = o * 256 + (((k >> 3) ^ (o & 7)) * 8) + (k & 7);
        lds[idx] = hi;
        lds[16384 + idx] = lo;
      }
    }
  }
  __syncthreads();

  const int row = bid * 64 + wv * 16 + l15;
  f32x4 acc[4] = {{0.f,0.f,0.f,0.f},{0.f,0.f,0.f,0.f},
                  {0.f,0.f,0.f,0.f},{0.f,0.f,0.f,0.f}};
  const float* xrow = x + (size_t)row * FIN;

  #pragma unroll
  for (int ks = 0; ks < 8; ++ks) {
    int k0 = ks * 32;
    float4 xa = *(const float4*)(xrow + k0 + kg * 8);
    float4 xb = *(const float4*)(xrow + k0 + kg * 8 + 4);
    float xv[8] = {xa.x, xa.y, xa.z, xa.w, xb.x, xb.y, xb.z, xb.w};
    bf16x8 ahi, alo;
    #pragma unroll
    for (int j = 0; j < 8; ++j) {
      unsigned short hi = f2bf(xv[j]);
      unsigned short lo = f2bf(xv[j] - bf2f(hi));
      ahi[j] = (short)hi;
      alo[j] = (short)lo;
    }
    int kgidx = ks * 4 + kg;
    #pragma unroll
    for (int ot = 0; ot < 4; ++ot) {
      int o = ot * 16 + l15;
      int base = o * 256 + ((kgidx ^ (o & 7)) * 8);
      bf16x8 bhi = *(const bf16x8*)&lds[base];
      bf16x8 blo = *(const bf16x8*)&lds[16384 + base];
      acc[ot] = __builtin_amdgcn_mfma_f32_16x16x32_bf16(ahi, bhi, acc[ot], 0, 0, 0);
      acc[ot] = __builtin_amdgcn_mfma_f32_16x16x32_bf16(ahi, blo, acc[ot], 0, 0, 0);
      acc[ot] = __builtin_amdgcn_mfma_f32_16x16x32_bf16(alo, bhi, acc[ot], 0, 0, 0);
    }
  }

  // el/er: reduce across the 16 col-lanes (same kg group)
  float aLv[4], aRv[4];
  #pragma unroll
  for (int ot = 0; ot < 4; ++ot) {
    aLv[ot] = a[ot * 16 + l15];
    aRv[ot] = a[64 + ot * 16 + l15];
  }
  #pragma unroll
  for (int jj = 0; jj < 4; ++jj) {
    float pl = 0.f, pr = 0.f;
    #pragma unroll
    for (int ot = 0; ot < 4; ++ot) {
      pl += acc[ot][jj] * aLv[ot];
      pr += acc[ot][jj] * aRv[ot];
    }
    #pragma unroll
    for (int s = 1; s < 16; s <<= 1) {
      pl += __shfl_xor(pl, s);
      pr += __shfl_xor(pr, s);
    }
    if (l15 == 0) {
      int grow = bid * 64 + wv * 16 + kg * 4 + jj;
      el[grow] = pl;
      er[grow] = pr;
    }
  }

  // phase 2: hi/lo split of h, scatter into the image layout (alias lds):
  // u16 idx = ((ks2*2+plane)*64 + o)*32 + (kg2 ^ ((o>>1)&3))*8 + j
  __syncthreads();
  #pragma unroll
  for (int ot = 0; ot < 4; ++ot) {
    int o = ot * 16 + l15;
    int xorv = (o >> 1) & 3;
    #pragma unroll
    for (int jj = 0; jj < 4; ++jj) {
      int m_loc = wv * 16 + kg * 4 + jj;
      int ks2 = m_loc >> 5;
      int kg2 = (m_loc >> 3) & 3;
      int j = m_loc & 7;
      int kgp = kg2 ^ xorv;
      float v = acc[ot][jj];
      unsigned short hi = f2bf(v);
      unsigned short lo = f2bf(v - bf2f(hi));
      int base = ((ks2 * 2 + 0) * 64 + o) * 32 + kgp * 8 + j;
      lds[base] = hi;
      lds[base + 2048] = lo;  // plane stride = 64*32 u16
    }
  }
  __syncthreads();

  // dump 16KB image contiguously to global
  {
    const uint4* src = (const uint4*)(const void*)lds;
    uint4* dst = (uint4*)(hS + (size_t)bid * 16384);
    #pragma unroll
    for (int i = 0; i < 4; ++i) dst[t + i * 256] = src[t + i * 256];
  }
}

// ---------------------------------------------------------------------------
// K2: masked-softmax attention as MFMA GEMM — registered-mask edition.
// 512 blocks x 256 thr; block owns 32 n-rows, wave wv owns m-window
// [wv*512,(wv+1)*512) = 16 chunks of 32 m. The wave's ENTIRE mask working set
// (32 rows x 16 words) is loaded ONCE in the prologue into 2 uint4/lane;
// per chunk the right word reaches the right lanes via one __shfl. The
// K-loop's only memory ops are L2-resident B-frags + er (1-ahead). No
// barriers/asm in the main loop. LDS = end combine only.
// ---------------------------------------------------------------------------
__global__ __launch_bounds__(256, 2) void k2_attn(
    const unsigned int* __restrict__ bm32, const unsigned char* __restrict__ hS,
    const float* __restrict__ el, const float* __restrict__ er,
    float* __restrict__ out) {
  __shared__ __align__(16) float cb[3 * 64 * 36];  // 27.6 KB combine buffer
  const int t = threadIdx.x;
  const int wv = t >> 6;
  const int l = t & 63;
  const int l15 = l & 15;
  const int kg = l >> 4;

  // XCD-bijective swizzle: 512 blocks, 64/XCD -> each XCD sees one batch
  int bid = blockIdx.x;
  int swz = (bid & 7) * 64 + (bid >> 3);
  int b = swz >> 6;
  int n0 = (swz & 63) * 32;

  const int row0 = n0 + l15;        // rt=0 rows
  const int row1 = n0 + 16 + l15;   // rt=1 rows
  const float eL0 = el[b * NN + row0];
  const float eL1 = el[b * NN + row1];
  const float* erp = er + b * NN + wv * 512;
  const unsigned char* hW = hS + (size_t)b * 32 * 16384 + (size_t)wv * 16 * 8192;
  const int laneoff = l15 * 64 + ((kg ^ ((l >> 1) & 3)) * 16);
  const int shift = kg * 8;

  // prologue: whole-window masks into registers. Lane l holds words
  // [row l15][wv*16 + kg*4 .. +3] (uint4); chunk c's word lives in lane
  // (c>>2)*16 + l15, component c&3.
  const unsigned int* bmp =
      bm32 + ((size_t)(b * NN + n0 + l15)) * 64 + wv * 16 + kg * 4;
  const uint4 M0 = *(const uint4*)bmp;            // rows n0..n0+15
  const uint4 M1 = *(const uint4*)(bmp + 16 * 64); // rows n0+16..n0+31

  f32x4 acc[2][4] = {{{0.f,0.f,0.f,0.f},{0.f,0.f,0.f,0.f},
                      {0.f,0.f,0.f,0.f},{0.f,0.f,0.f,0.f}},
                     {{0.f,0.f,0.f,0.f},{0.f,0.f,0.f,0.f},
                      {0.f,0.f,0.f,0.f},{0.f,0.f,0.f,0.f}}};
  float S0 = 0.f, S1 = 0.f;

  float4 evc0 = *(const float4*)(erp + kg * 8);
  float4 evc1 = *(const float4*)(erp + kg * 8 + 4);

  #pragma unroll
  for (int c = 0; c < 16; ++c) {
    // B-fragments straight from L2 (consumed after j-loop)
    bf16x8 curH[4], curL[4];
    {
      const unsigned char* p_ = hW + (size_t)c * 8192 + laneoff;
      #pragma unroll
      for (int ot = 0; ot < 4; ++ot) {
        curH[ot] = *(const bf16x8*)(p_ + ot * 1024);
        curL[ot] = *(const bf16x8*)(p_ + ot * 1024 + 4096);
      }
    }
    float4 evn0, evn1;
    if (c < 15) {
      evn0 = *(const float4*)(erp + (c + 1) * 32 + kg * 8);
      evn1 = *(const float4*)(erp + (c + 1) * 32 + kg * 8 + 4);
    }

    // mask word for this chunk, routed from the prologue registers
    const int msrc = (c >> 2) * 16 + l15;
    const unsigned int m0sel = (c & 3) == 0 ? M0.x : (c & 3) == 1 ? M0.y
                             : (c & 3) == 2 ? M0.z : M0.w;
    const unsigned int m1sel = (c & 3) == 0 ? M1.x : (c & 3) == 1 ? M1.y
                             : (c & 3) == 2 ? M1.z : M1.w;
    const unsigned int w0c = (unsigned int)__shfl((int)m0sel, msrc);
    const unsigned int w1c = (unsigned int)__shfl((int)m1sel, msrc);

    float ee[8] = {evc0.x, evc0.y, evc0.z, evc0.w,
                   evc1.x, evc1.y, evc1.z, evc1.w};

    bf16x8 af0h, af0l, af1h, af1l;
    #pragma unroll
    for (int j = 0; j < 8; ++j) {
      float e0 = eL0 + ee[j];
      e0 = fmaxf(e0, ALPHA * e0);
      float w0 = ((w0c >> (shift + j)) & 1u) ? __expf(e0) : 0.f;
      unsigned short h0 = f2bf(w0);
      float w0h = bf2f(h0);
      unsigned short l0 = f2bf(w0 - w0h);
      af0h[j] = (short)h0;
      af0l[j] = (short)l0;
      S0 += w0h + bf2f(l0);               // denom == effective numer weight

      float e1 = eL1 + ee[j];
      e1 = fmaxf(e1, ALPHA * e1);
      float w1 = ((w1c >> (shift + j)) & 1u) ? __expf(e1) : 0.f;
      unsigned short h1 = f2bf(w1);
      float w1h = bf2f(h1);
      unsigned short l1 = f2bf(w1 - w1h);
      af1h[j] = (short)h1;
      af1l[j] = (short)l1;
      S1 += w1h + bf2f(l1);
    }

    #pragma unroll
    for (int ot = 0; ot < 4; ++ot) {
      acc[0][ot] = __builtin_amdgcn_mfma_f32_16x16x32_bf16(af0h, curH[ot], acc[0][ot], 0, 0, 0);
      acc[0][ot] = __builtin_amdgcn_mfma_f32_16x16x32_bf16(af0h, curL[ot], acc[0][ot], 0, 0, 0);
      acc[0][ot] = __builtin_amdgcn_mfma_f32_16x16x32_bf16(af0l, curH[ot], acc[0][ot], 0, 0, 0);
      acc[1][ot] = __builtin_amdgcn_mfma_f32_16x16x32_bf16(af1h, curH[ot], acc[1][ot], 0, 0, 0);
      acc[1][ot] = __builtin_amdgcn_mfma_f32_16x16x32_bf16(af1h, curL[ot], acc[1][ot], 0, 0, 0);
      acc[1][ot] = __builtin_amdgcn_mfma_f32_16x16x32_bf16(af1l, curH[ot], acc[1][ot], 0, 0, 0);
    }

    if (c < 15) { evc0 = evn0; evc1 = evn1; }
  }

  // per-wave S reduce across kg groups (replicates row-l15 denom to all lanes)
  S0 += __shfl_xor(S0, 16); S0 += __shfl_xor(S0, 32);
  S1 += __shfl_xor(S1, 16); S1 += __shfl_xor(S1, 32);

  // cross-wave combine of m-window partials: waves 1..3 publish, wave 0 sums
  __syncthreads();
  if (wv > 0) {
    float* dst = cb + ((wv - 1) * 64 + l) * 36;
    #pragma unroll
    for (int ot = 0; ot < 4; ++ot) {
      *(f32x4*)(dst + ot * 4)      = acc[0][ot];
      *(f32x4*)(dst + 16 + ot * 4) = acc[1][ot];
    }
    dst[32] = S0;
    dst[33] = S1;
  }
  __syncthreads();
  if (wv != 0) return;

  #pragma unroll
  for (int p = 0; p < 3; ++p) {
    const float* src = cb + (p * 64 + l) * 36;
    #pragma unroll
    for (int ot = 0; ot < 4; ++ot) {
      acc[0][ot] += *(const f32x4*)(src + ot * 4);
      acc[1][ot] += *(const f32x4*)(src + 16 + ot * 4);
    }
    S0 += src[32];
    S1 += src[33];
  }

  float Sj0[4], Sj1[4];
  #pragma unroll
  for (int jj = 0; jj < 4; ++jj) {
    Sj0[jj] = __shfl(S0, kg * 4 + jj);
    Sj1[jj] = __shfl(S1, kg * 4 + jj);
  }
  #pragma unroll
  for (int ot = 0; ot < 4; ++ot) {
    #pragma unroll
    for (int jj = 0; jj < 4; ++jj) {
      float v0 = acc[0][ot][jj] / Sj0[jj];
      float r0 = v0 > 0.f ? v0 : expm1f(v0);
      out[((size_t)b * NN + n0 + kg * 4 + jj) * FOUT + ot * 16 + l15] = r0;
      float v1 = acc[1][ot][jj] / Sj1[jj];
      float r1 = v1 > 0.f ? v1 : expm1f(v1);
      out[((size_t)b * NN + n0 + 16 + kg * 4 + jj) * FOUT + ot * 16 + l15] = r1;
    }
  }
}

extern "C" void kernel_launch(void* const* d_in, const int* in_sizes, int n_in,
                              void* d_out, int out_size, void* d_ws, size_t ws_size,
                              hipStream_t stream) {
  const float* x   = (const float*)d_in[0];
  const int*   adj = (const int*)d_in[1];
  const float* W   = (const float*)d_in[2];
  const float* a   = (const float*)d_in[3];
  float* out = (float*)d_out;

  // ws layout: hS images (4MB) | el (64KB) | er (64KB) | bitmask (4MB)
  unsigned char* hS = (unsigned char*)d_ws;
  float* el = (float*)(hS + (size_t)BATCH * 32 * 16384);
  float* er = el + BATCH * NN;
  unsigned int* bm32 = (unsigned int*)(er + BATCH * NN);

  hipLaunchKernelGGL(k1_fused, dim3(2304), dim3(256), 0, stream,
                     x, adj, W, a, el, er, hS, bm32);
  hipLaunchKernelGGL(k2_attn, dim3(512), dim3(256), 0, stream,
                     bm32, hS, el, er, out);
}

// Round 11
// 65.132 us; speedup vs baseline: 4.0944x; 2.5335x over previous
//
#include <hip/hip_runtime.h>
#include <math.h>

#define BATCH 8
#define NN 2048
#define FIN 256
#define FOUT 64
#define ALPHA 0.2f

typedef __attribute__((ext_vector_type(8))) short bf16x8;
typedef __attribute__((ext_vector_type(4))) float f32x4;

static __device__ __forceinline__ unsigned short f2bf(float f) {
  unsigned int u = __float_as_uint(f);
  u += 0x7fffu + ((u >> 16) & 1u);
  return (unsigned short)(u >> 16);
}
static __device__ __forceinline__ float bf2f(unsigned short h) {
  return __uint_as_float(((unsigned int)h) << 16);
}

// ---------------------------------------------------------------------------
// K1f: fused. Blocks 0..255: h = x@W via MFMA (hi/lo bf16 split), el/er,
// pre-swizzled h image (IDENTICAL numerics to prior rounds).
// Blocks 256..2303 (8192 waves): adj -> 1-bit mask (4MB). Each wave: 16 int4
// loads (1KB/instr, coalesced, exact coverage), sched_barrier, then per
// f-block: 4 __ballot's (uniform u64 per int4 component) + lanes 0..7
// byte-transpose into chunk words -- ZERO DS ops (round-10 pack was 48
// serial-latency shuffles/wave). Word bit layout: for m_in_chunk = kg*8+j,
// bit = (j&3)*8 + (j>>2) + 2*kg  (K2 uses the matching extract).
// ---------------------------------------------------------------------------
__global__ __launch_bounds__(256) void k1_fused(
    const float* __restrict__ x, const int* __restrict__ adj,
    const float* __restrict__ W, const float* __restrict__ a,
    float* __restrict__ el, float* __restrict__ er,
    unsigned char* __restrict__ hS, unsigned int* __restrict__ bm32) {
  __shared__ __align__(16) unsigned short lds[32768];  // 64 KB
  const int bid = blockIdx.x;
  const int t = threadIdx.x;
  const int wv = t >> 6;
  const int l = t & 63;

  if (bid >= 256) {
    // ---- streaming role: adj -> bitmask via ballot-transpose ----
    const unsigned int wslot = (unsigned int)(bid - 256) * 4u + (unsigned int)wv;
    const int4* adj4 = (const int4*)adj;
    int4 v[16];
    #pragma unroll
    for (int i = 0; i < 16; ++i) {
      unsigned int f = wslot + (unsigned int)i * 8192u;  // f < 131072 exact
      v[i] = adj4[(size_t)f * 64 + l];
    }
    __builtin_amdgcn_sched_barrier(0);   // keep the 16 loads issued together
    #pragma unroll
    for (int i = 0; i < 16; ++i) {
      unsigned int f = wslot + (unsigned int)i * 8192u;
      unsigned long long B0 = __ballot(v[i].x > 0);
      unsigned long long B1 = __ballot(v[i].y > 0);
      unsigned long long B2 = __ballot(v[i].z > 0);
      unsigned long long B3 = __ballot(v[i].w > 0);
      if (l < 8) {
        int sh = l * 8;
        unsigned int w = ((unsigned int)((B0 >> sh) & 0xFFull))
                       | ((unsigned int)((B1 >> sh) & 0xFFull) << 8)
                       | ((unsigned int)((B2 >> sh) & 0xFFull) << 16)
                       | ((unsigned int)((B3 >> sh) & 0xFFull) << 24);
        bm32[(size_t)(f >> 3) * 64 + (f & 7) * 8 + l] = w;
      }
    }
    return;
  }

  // ---- h role (unchanged numerics) ----
  const int l15 = l & 15;
  const int kg = l >> 4;

  // phase 0: stage W as bf16 hi/lo planes, XOR-swizzled:
  // u16 idx = plane*16384 + o*256 + ((k>>3)^(o&7))*8 + (k&7)
  {
    const float4* W4 = (const float4*)W;
    #pragma unroll
    for (int i = 0; i < 16; ++i) {
      int f = t + i * 256;            // float4 index, 0..4095
      float4 v = W4[f];
      int k = f >> 4;                 // W row 0..255
      int ob = (f & 15) * 4;
      float vv[4] = {v.x, v.y, v.z, v.w};
      #pragma unroll
      for (int c = 0; c < 4; ++c) {
        int o = ob + c;
        unsigned short hi = f2bf(vv[c]);
        unsigned short lo = f2bf(vv[c] - bf2f(hi));
        int idx = o * 256 + (((k >> 3) ^ (o & 7)) * 8) + (k & 7);
        lds[idx] = hi;
        lds[16384 + idx] = lo;
      }
    }
  }
  __syncthreads();

  const int row = bid * 64 + wv * 16 + l15;
  f32x4 acc[4] = {{0.f,0.f,0.f,0.f},{0.f,0.f,0.f,0.f},
                  {0.f,0.f,0.f,0.f},{0.f,0.f,0.f,0.f}};
  const float* xrow = x + (size_t)row * FIN;

  #pragma unroll
  for (int ks = 0; ks < 8; ++ks) {
    int k0 = ks * 32;
    float4 xa = *(const float4*)(xrow + k0 + kg * 8);
    float4 xb = *(const float4*)(xrow + k0 + kg * 8 + 4);
    float xv[8] = {xa.x, xa.y, xa.z, xa.w, xb.x, xb.y, xb.z, xb.w};
    bf16x8 ahi, alo;
    #pragma unroll
    for (int j = 0; j < 8; ++j) {
      unsigned short hi = f2bf(xv[j]);
      unsigned short lo = f2bf(xv[j] - bf2f(hi));
      ahi[j] = (short)hi;
      alo[j] = (short)lo;
    }
    int kgidx = ks * 4 + kg;
    #pragma unroll
    for (int ot = 0; ot < 4; ++ot) {
      int o = ot * 16 + l15;
      int base = o * 256 + ((kgidx ^ (o & 7)) * 8);
      bf16x8 bhi = *(const bf16x8*)&lds[base];
      bf16x8 blo = *(const bf16x8*)&lds[16384 + base];
      acc[ot] = __builtin_amdgcn_mfma_f32_16x16x32_bf16(ahi, bhi, acc[ot], 0, 0, 0);
      acc[ot] = __builtin_amdgcn_mfma_f32_16x16x32_bf16(ahi, blo, acc[ot], 0, 0, 0);
      acc[ot] = __builtin_amdgcn_mfma_f32_16x16x32_bf16(alo, bhi, acc[ot], 0, 0, 0);
    }
  }

  // el/er: reduce across the 16 col-lanes (same kg group)
  float aLv[4], aRv[4];
  #pragma unroll
  for (int ot = 0; ot < 4; ++ot) {
    aLv[ot] = a[ot * 16 + l15];
    aRv[ot] = a[64 + ot * 16 + l15];
  }
  #pragma unroll
  for (int jj = 0; jj < 4; ++jj) {
    float pl = 0.f, pr = 0.f;
    #pragma unroll
    for (int ot = 0; ot < 4; ++ot) {
      pl += acc[ot][jj] * aLv[ot];
      pr += acc[ot][jj] * aRv[ot];
    }
    #pragma unroll
    for (int s = 1; s < 16; s <<= 1) {
      pl += __shfl_xor(pl, s);
      pr += __shfl_xor(pr, s);
    }
    if (l15 == 0) {
      int grow = bid * 64 + wv * 16 + kg * 4 + jj;
      el[grow] = pl;
      er[grow] = pr;
    }
  }

  // phase 2: hi/lo split of h, scatter into the image layout (alias lds):
  // u16 idx = ((ks2*2+plane)*64 + o)*32 + (kg2 ^ ((o>>1)&3))*8 + j
  __syncthreads();
  #pragma unroll
  for (int ot = 0; ot < 4; ++ot) {
    int o = ot * 16 + l15;
    int xorv = (o >> 1) & 3;
    #pragma unroll
    for (int jj = 0; jj < 4; ++jj) {
      int m_loc = wv * 16 + kg * 4 + jj;
      int ks2 = m_loc >> 5;
      int kg2 = (m_loc >> 3) & 3;
      int j = m_loc & 7;
      int kgp = kg2 ^ xorv;
      float v = acc[ot][jj];
      unsigned short hi = f2bf(v);
      unsigned short lo = f2bf(v - bf2f(hi));
      int base = ((ks2 * 2 + 0) * 64 + o) * 32 + kgp * 8 + j;
      lds[base] = hi;
      lds[base + 2048] = lo;  // plane stride = 64*32 u16
    }
  }
  __syncthreads();

  // dump 16KB image contiguously to global
  {
    const uint4* src = (const uint4*)(const void*)lds;
    uint4* dst = (uint4*)(hS + (size_t)bid * 16384);
    #pragma unroll
    for (int i = 0; i < 4; ++i) dst[t + i * 256] = src[t + i * 256];
  }
}

// ---------------------------------------------------------------------------
// K2: masked-softmax attention as MFMA GEMM — ROLLED loop (spill-proof).
// 512 blocks x 256 thr; block owns 32 n-rows, wave wv owns m-window
// [wv*512,(wv+1)*512) = 16 chunks of 32 m. #pragma unroll 1 prevents the
// round-10 failure (compiler hoisted many chunks' 128B/lane B-frag loads ->
// 1.5KB/thread scratch spill, 193MB write traffic). Per iteration: B-frags
// load at top (consumed after the ~450-cyc j-loop -> L2 latency covered),
// mask word + er prefetched 1-ahead (named regs). Bit extract matches the
// producer's ballot layout: bit = 2*kg + (j&3)*8 + (j>>2).
// ---------------------------------------------------------------------------
__global__ __launch_bounds__(256, 3) void k2_attn(
    const unsigned int* __restrict__ bm32, const unsigned char* __restrict__ hS,
    const float* __restrict__ el, const float* __restrict__ er,
    float* __restrict__ out) {
  __shared__ __align__(16) float cb[3 * 64 * 36];  // 27.6 KB combine buffer
  const int t = threadIdx.x;
  const int wv = t >> 6;
  const int l = t & 63;
  const int l15 = l & 15;
  const int kg = l >> 4;

  // XCD-bijective swizzle: 512 blocks, 64/XCD -> each XCD sees one batch
  int bid = blockIdx.x;
  int swz = (bid & 7) * 64 + (bid >> 3);
  int b = swz >> 6;
  int n0 = (swz & 63) * 32;

  const int row0 = n0 + l15;        // rt=0 rows
  const int row1 = n0 + 16 + l15;   // rt=1 rows
  const float eL0 = el[b * NN + row0];
  const float eL1 = el[b * NN + row1];
  const unsigned int* bmr0 = bm32 + ((size_t)(b * NN + row0)) * 64 + wv * 16;
  const unsigned int* bmr1 = bm32 + ((size_t)(b * NN + row1)) * 64 + wv * 16;
  const float* erp = er + b * NN + wv * 512;
  const unsigned char* hW = hS + (size_t)b * 32 * 16384 + (size_t)wv * 16 * 8192;
  const int laneoff = l15 * 64 + ((kg ^ ((l >> 1) & 3)) * 16);
  const int sh2 = kg * 2;

  f32x4 acc[2][4] = {{{0.f,0.f,0.f,0.f},{0.f,0.f,0.f,0.f},
                      {0.f,0.f,0.f,0.f},{0.f,0.f,0.f,0.f}},
                     {{0.f,0.f,0.f,0.f},{0.f,0.f,0.f,0.f},
                      {0.f,0.f,0.f,0.f},{0.f,0.f,0.f,0.f}}};
  float S0 = 0.f, S1 = 0.f;

  // prologue: mask words + er for chunk 0
  unsigned int w0c = bmr0[0], w1c = bmr1[0];
  float4 evc0 = *(const float4*)(erp + kg * 8);
  float4 evc1 = *(const float4*)(erp + kg * 8 + 4);

  #pragma unroll 1
  for (int c = 0; c < 16; ++c) {
    // B-fragments straight from L2 (consumed after the j-loop)
    bf16x8 curH[4], curL[4];
    {
      const unsigned char* p_ = hW + (size_t)c * 8192 + laneoff;
      #pragma unroll
      for (int ot = 0; ot < 4; ++ot) {
        curH[ot] = *(const bf16x8*)(p_ + ot * 1024);
        curL[ot] = *(const bf16x8*)(p_ + ot * 1024 + 4096);
      }
    }
    // 1-ahead prefetch (unconditional: one-past reads stay inside d_ws)
    unsigned int w0n = bmr0[c + 1];
    unsigned int w1n = bmr1[c + 1];
    float4 evn0 = *(const float4*)(erp + (c + 1) * 32 + kg * 8);
    float4 evn1 = *(const float4*)(erp + (c + 1) * 32 + kg * 8 + 4);

    float ee[8] = {evc0.x, evc0.y, evc0.z, evc0.w,
                   evc1.x, evc1.y, evc1.z, evc1.w};

    bf16x8 af0h, af0l, af1h, af1l;
    #pragma unroll
    for (int j = 0; j < 8; ++j) {
      const int bitc = (j & 3) * 8 + (j >> 2);   // + 2*kg at runtime
      float e0 = eL0 + ee[j];
      e0 = fmaxf(e0, ALPHA * e0);
      float w0 = ((w0c >> (sh2 + bitc)) & 1u) ? __expf(e0) : 0.f;
      unsigned short h0 = f2bf(w0);
      float w0h = bf2f(h0);
      unsigned short l0 = f2bf(w0 - w0h);
      af0h[j] = (short)h0;
      af0l[j] = (short)l0;
      S0 += w0h + bf2f(l0);               // denom == effective numer weight

      float e1 = eL1 + ee[j];
      e1 = fmaxf(e1, ALPHA * e1);
      float w1 = ((w1c >> (sh2 + bitc)) & 1u) ? __expf(e1) : 0.f;
      unsigned short h1 = f2bf(w1);
      float w1h = bf2f(h1);
      unsigned short l1 = f2bf(w1 - w1h);
      af1h[j] = (short)h1;
      af1l[j] = (short)l1;
      S1 += w1h + bf2f(l1);
    }

    #pragma unroll
    for (int ot = 0; ot < 4; ++ot) {
      acc[0][ot] = __builtin_amdgcn_mfma_f32_16x16x32_bf16(af0h, curH[ot], acc[0][ot], 0, 0, 0);
      acc[0][ot] = __builtin_amdgcn_mfma_f32_16x16x32_bf16(af0h, curL[ot], acc[0][ot], 0, 0, 0);
      acc[0][ot] = __builtin_amdgcn_mfma_f32_16x16x32_bf16(af0l, curH[ot], acc[0][ot], 0, 0, 0);
      acc[1][ot] = __builtin_amdgcn_mfma_f32_16x16x32_bf16(af1h, curH[ot], acc[1][ot], 0, 0, 0);
      acc[1][ot] = __builtin_amdgcn_mfma_f32_16x16x32_bf16(af1h, curL[ot], acc[1][ot], 0, 0, 0);
      acc[1][ot] = __builtin_amdgcn_mfma_f32_16x16x32_bf16(af1l, curH[ot], acc[1][ot], 0, 0, 0);
    }

    w0c = w0n; w1c = w1n; evc0 = evn0; evc1 = evn1;
  }

  // per-wave S reduce across kg groups (replicates row-l15 denom to all lanes)
  S0 += __shfl_xor(S0, 16); S0 += __shfl_xor(S0, 32);
  S1 += __shfl_xor(S1, 16); S1 += __shfl_xor(S1, 32);

  // cross-wave combine of m-window partials: waves 1..3 publish, wave 0 sums
  __syncthreads();
  if (wv > 0) {
    float* dst = cb + ((wv - 1) * 64 + l) * 36;
    #pragma unroll
    for (int ot = 0; ot < 4; ++ot) {
      *(f32x4*)(dst + ot * 4)      = acc[0][ot];
      *(f32x4*)(dst + 16 + ot * 4) = acc[1][ot];
    }
    dst[32] = S0;
    dst[33] = S1;
  }
  __syncthreads();
  if (wv != 0) return;

  #pragma unroll
  for (int p = 0; p < 3; ++p) {
    const float* src = cb + (p * 64 + l) * 36;
    #pragma unroll
    for (int ot = 0; ot < 4; ++ot) {
      acc[0][ot] += *(const f32x4*)(src + ot * 4);
      acc[1][ot] += *(const f32x4*)(src + 16 + ot * 4);
    }
    S0 += src[32];
    S1 += src[33];
  }

  float Sj0[4], Sj1[4];
  #pragma unroll
  for (int jj = 0; jj < 4; ++jj) {
    Sj0[jj] = __shfl(S0, kg * 4 + jj);
    Sj1[jj] = __shfl(S1, kg * 4 + jj);
  }
  #pragma unroll
  for (int ot = 0; ot < 4; ++ot) {
    #pragma unroll
    for (int jj = 0; jj < 4; ++jj) {
      float v0 = acc[0][ot][jj] / Sj0[jj];
      float r0 = v0 > 0.f ? v0 : expm1f(v0);
      out[((size_t)b * NN + n0 + kg * 4 + jj) * FOUT + ot * 16 + l15] = r0;
      float v1 = acc[1][ot][jj] / Sj1[jj];
      float r1 = v1 > 0.f ? v1 : expm1f(v1);
      out[((size_t)b * NN + n0 + 16 + kg * 4 + jj) * FOUT + ot * 16 + l15] = r1;
    }
  }
}

extern "C" void kernel_launch(void* const* d_in, const int* in_sizes, int n_in,
                              void* d_out, int out_size, void* d_ws, size_t ws_size,
                              hipStream_t stream) {
  const float* x   = (const float*)d_in[0];
  const int*   adj = (const int*)d_in[1];
  const float* W   = (const float*)d_in[2];
  const float* a   = (const float*)d_in[3];
  float* out = (float*)d_out;

  // ws layout: hS images (4MB) | el (64KB) | er (64KB) | bitmask (4MB)
  unsigned char* hS = (unsigned char*)d_ws;
  float* el = (float*)(hS + (size_t)BATCH * 32 * 16384);
  float* er = el + BATCH * NN;
  unsigned int* bm32 = (unsigned int*)(er + BATCH * NN);

  hipLaunchKernelGGL(k1_fused, dim3(2304), dim3(256), 0, stream,
                     x, adj, W, a, el, er, hS, bm32);
  hipLaunchKernelGGL(k2_attn, dim3(512), dim3(256), 0, stream,
                     bm32, hS, el, er, out);
}

// Round 12
// 63.562 us; speedup vs baseline: 4.1955x; 1.0247x over previous
//
#include <hip/hip_runtime.h>
#include <math.h>

#define BATCH 8
#define NN 2048
#define FIN 256
#define FOUT 64
#define ALPHA 0.2f

typedef __attribute__((ext_vector_type(8))) short bf16x8;
typedef __attribute__((ext_vector_type(4))) float f32x4;

static __device__ __forceinline__ unsigned short f2bf(float f) {
  unsigned int u = __float_as_uint(f);
  u += 0x7fffu + ((u >> 16) & 1u);
  return (unsigned short)(u >> 16);
}
static __device__ __forceinline__ float bf2f(unsigned short h) {
  return __uint_as_float(((unsigned int)h) << 16);
}

// ---------------------------------------------------------------------------
// K1f: fused. Blocks 0..255: h = x@W via MFMA (hi/lo bf16 split), el/er,
// pre-swizzled h image (IDENTICAL numerics to prior rounds).
// Blocks 256..1279 (4096 waves): adj -> 1-bit mask (4MB). Each wave: 4
// software-pipelined bursts of 8 int4 loads (1KB/instr, coalesced); burst
// t+1 is issued BEFORE packing burst t (sched_barrier pins it) so 8-16
// loads stay in flight continuously (round-11 failure: one-shot bursts +
// 4.5 dispatch rounds never saturated HBM). Pack: 4 ballots/f-block +
// lanes 0..7 byte-transpose, zero DS ops. Bit layout unchanged:
// for m_in_chunk = kg*8+j, bit = (j&3)*8 + (j>>2) + 2*kg.
// ---------------------------------------------------------------------------
__global__ __launch_bounds__(256) void k1_fused(
    const float* __restrict__ x, const int* __restrict__ adj,
    const float* __restrict__ W, const float* __restrict__ a,
    float* __restrict__ el, float* __restrict__ er,
    unsigned char* __restrict__ hS, unsigned int* __restrict__ bm32) {
  __shared__ __align__(16) unsigned short lds[32768];  // 64 KB
  const int bid = blockIdx.x;
  const int t = threadIdx.x;
  const int wv = t >> 6;
  const int l = t & 63;

  if (bid >= 256) {
    // ---- streaming role: adj -> bitmask, pipelined bursts ----
    const unsigned int wslot = (unsigned int)(bid - 256) * 4u + (unsigned int)wv;
    const int4* adj4 = (const int4*)adj;
    int4 A[8], Bv[8];
    #pragma unroll
    for (int i = 0; i < 8; ++i)
      A[i] = adj4[(size_t)(wslot + (unsigned int)i * 4096u) * 64 + l];

    #pragma unroll
    for (int tt = 0; tt < 4; ++tt) {
      if (tt < 3) {
        #pragma unroll
        for (int i = 0; i < 8; ++i)
          Bv[i] = adj4[(size_t)(wslot + (unsigned int)((tt + 1) * 8 + i) * 4096u) * 64 + l];
      }
      __builtin_amdgcn_sched_barrier(0);   // pack below; next loads above
      #pragma unroll
      for (int i = 0; i < 8; ++i) {
        unsigned int f = wslot + (unsigned int)(tt * 8 + i) * 4096u;
        unsigned long long B0 = __ballot(A[i].x > 0);
        unsigned long long B1 = __ballot(A[i].y > 0);
        unsigned long long B2 = __ballot(A[i].z > 0);
        unsigned long long B3 = __ballot(A[i].w > 0);
        if (l < 8) {
          int sh = l * 8;
          unsigned int w = ((unsigned int)((B0 >> sh) & 0xFFull))
                         | ((unsigned int)((B1 >> sh) & 0xFFull) << 8)
                         | ((unsigned int)((B2 >> sh) & 0xFFull) << 16)
                         | ((unsigned int)((B3 >> sh) & 0xFFull) << 24);
          bm32[(size_t)(f >> 3) * 64 + (f & 7) * 8 + l] = w;
        }
      }
      if (tt < 3) {
        #pragma unroll
        for (int i = 0; i < 8; ++i) A[i] = Bv[i];   // SSA rename under unroll
      }
    }
    return;
  }

  // ---- h role (unchanged numerics) ----
  const int l15 = l & 15;
  const int kg = l >> 4;

  // phase 0: stage W as bf16 hi/lo planes, XOR-swizzled:
  // u16 idx = plane*16384 + o*256 + ((k>>3)^(o&7))*8 + (k&7)
  {
    const float4* W4 = (const float4*)W;
    #pragma unroll
    for (int i = 0; i < 16; ++i) {
      int f = t + i * 256;            // float4 index, 0..4095
      float4 v = W4[f];
      int k = f >> 4;                 // W row 0..255
      int ob = (f & 15) * 4;
      float vv[4] = {v.x, v.y, v.z, v.w};
      #pragma unroll
      for (int c = 0; c < 4; ++c) {
        int o = ob + c;
        unsigned short hi = f2bf(vv[c]);
        unsigned short lo = f2bf(vv[c] - bf2f(hi));
        int idx = o * 256 + (((k >> 3) ^ (o & 7)) * 8) + (k & 7);
        lds[idx] = hi;
        lds[16384 + idx] = lo;
      }
    }
  }
  __syncthreads();

  const int row = bid * 64 + wv * 16 + l15;
  f32x4 acc[4] = {{0.f,0.f,0.f,0.f},{0.f,0.f,0.f,0.f},
                  {0.f,0.f,0.f,0.f},{0.f,0.f,0.f,0.f}};
  const float* xrow = x + (size_t)row * FIN;

  #pragma unroll
  for (int ks = 0; ks < 8; ++ks) {
    int k0 = ks * 32;
    float4 xa = *(const float4*)(xrow + k0 + kg * 8);
    float4 xb = *(const float4*)(xrow + k0 + kg * 8 + 4);
    float xv[8] = {xa.x, xa.y, xa.z, xa.w, xb.x, xb.y, xb.z, xb.w};
    bf16x8 ahi, alo;
    #pragma unroll
    for (int j = 0; j < 8; ++j) {
      unsigned short hi = f2bf(xv[j]);
      unsigned short lo = f2bf(xv[j] - bf2f(hi));
      ahi[j] = (short)hi;
      alo[j] = (short)lo;
    }
    int kgidx = ks * 4 + kg;
    #pragma unroll
    for (int ot = 0; ot < 4; ++ot) {
      int o = ot * 16 + l15;
      int base = o * 256 + ((kgidx ^ (o & 7)) * 8);
      bf16x8 bhi = *(const bf16x8*)&lds[base];
      bf16x8 blo = *(const bf16x8*)&lds[16384 + base];
      acc[ot] = __builtin_amdgcn_mfma_f32_16x16x32_bf16(ahi, bhi, acc[ot], 0, 0, 0);
      acc[ot] = __builtin_amdgcn_mfma_f32_16x16x32_bf16(ahi, blo, acc[ot], 0, 0, 0);
      acc[ot] = __builtin_amdgcn_mfma_f32_16x16x32_bf16(alo, bhi, acc[ot], 0, 0, 0);
    }
  }

  // el/er: reduce across the 16 col-lanes (same kg group)
  float aLv[4], aRv[4];
  #pragma unroll
  for (int ot = 0; ot < 4; ++ot) {
    aLv[ot] = a[ot * 16 + l15];
    aRv[ot] = a[64 + ot * 16 + l15];
  }
  #pragma unroll
  for (int jj = 0; jj < 4; ++jj) {
    float pl = 0.f, pr = 0.f;
    #pragma unroll
    for (int ot = 0; ot < 4; ++ot) {
      pl += acc[ot][jj] * aLv[ot];
      pr += acc[ot][jj] * aRv[ot];
    }
    #pragma unroll
    for (int s = 1; s < 16; s <<= 1) {
      pl += __shfl_xor(pl, s);
      pr += __shfl_xor(pr, s);
    }
    if (l15 == 0) {
      int grow = bid * 64 + wv * 16 + kg * 4 + jj;
      el[grow] = pl;
      er[grow] = pr;
    }
  }

  // phase 2: hi/lo split of h, scatter into the image layout (alias lds):
  // u16 idx = ((ks2*2+plane)*64 + o)*32 + (kg2 ^ ((o>>1)&3))*8 + j
  __syncthreads();
  #pragma unroll
  for (int ot = 0; ot < 4; ++ot) {
    int o = ot * 16 + l15;
    int xorv = (o >> 1) & 3;
    #pragma unroll
    for (int jj = 0; jj < 4; ++jj) {
      int m_loc = wv * 16 + kg * 4 + jj;
      int ks2 = m_loc >> 5;
      int kg2 = (m_loc >> 3) & 3;
      int j = m_loc & 7;
      int kgp = kg2 ^ xorv;
      float v = acc[ot][jj];
      unsigned short hi = f2bf(v);
      unsigned short lo = f2bf(v - bf2f(hi));
      int base = ((ks2 * 2 + 0) * 64 + o) * 32 + kgp * 8 + j;
      lds[base] = hi;
      lds[base + 2048] = lo;  // plane stride = 64*32 u16
    }
  }
  __syncthreads();

  // dump 16KB image contiguously to global
  {
    const uint4* src = (const uint4*)(const void*)lds;
    uint4* dst = (uint4*)(hS + (size_t)bid * 16384);
    #pragma unroll
    for (int i = 0; i < 4; ++i) dst[t + i * 256] = src[t + i * 256];
  }
}

// ---------------------------------------------------------------------------
// K2: masked-softmax attention as MFMA GEMM — rolled loop (spill-proof),
// bitmask masks, S += w denominator (dropped hi/lo re-add: <=2^-17 rel).
// 512 blocks x 256 thr; block owns 32 n-rows, wave wv owns m-window
// [wv*512,(wv+1)*512) = 16 chunks of 32 m. Per iteration: B-frags load at
// top (consumed after the ~500-cyc j-loop -> L2 latency covered), mask word
// + er prefetched 1-ahead (named regs). Bit extract matches producer:
// bit = 2*kg + (j&3)*8 + (j>>2).
// ---------------------------------------------------------------------------
__global__ __launch_bounds__(256, 3) void k2_attn(
    const unsigned int* __restrict__ bm32, const unsigned char* __restrict__ hS,
    const float* __restrict__ el, const float* __restrict__ er,
    float* __restrict__ out) {
  __shared__ __align__(16) float cb[3 * 64 * 36];  // 27.6 KB combine buffer
  const int t = threadIdx.x;
  const int wv = t >> 6;
  const int l = t & 63;
  const int l15 = l & 15;
  const int kg = l >> 4;

  // XCD-bijective swizzle: 512 blocks, 64/XCD -> each XCD sees one batch
  int bid = blockIdx.x;
  int swz = (bid & 7) * 64 + (bid >> 3);
  int b = swz >> 6;
  int n0 = (swz & 63) * 32;

  const int row0 = n0 + l15;        // rt=0 rows
  const int row1 = n0 + 16 + l15;   // rt=1 rows
  const float eL0 = el[b * NN + row0];
  const float eL1 = el[b * NN + row1];
  const unsigned int* bmr0 = bm32 + ((size_t)(b * NN + row0)) * 64 + wv * 16;
  const unsigned int* bmr1 = bm32 + ((size_t)(b * NN + row1)) * 64 + wv * 16;
  const float* erp = er + b * NN + wv * 512;
  const unsigned char* hW = hS + (size_t)b * 32 * 16384 + (size_t)wv * 16 * 8192;
  const int laneoff = l15 * 64 + ((kg ^ ((l >> 1) & 3)) * 16);
  const int sh2 = kg * 2;

  f32x4 acc[2][4] = {{{0.f,0.f,0.f,0.f},{0.f,0.f,0.f,0.f},
                      {0.f,0.f,0.f,0.f},{0.f,0.f,0.f,0.f}},
                     {{0.f,0.f,0.f,0.f},{0.f,0.f,0.f,0.f},
                      {0.f,0.f,0.f,0.f},{0.f,0.f,0.f,0.f}}};
  float S0 = 0.f, S1 = 0.f;

  // prologue: mask words + er for chunk 0
  unsigned int w0c = bmr0[0], w1c = bmr1[0];
  float4 evc0 = *(const float4*)(erp + kg * 8);
  float4 evc1 = *(const float4*)(erp + kg * 8 + 4);

  #pragma unroll 1
  for (int c = 0; c < 16; ++c) {
    // B-fragments straight from L2 (consumed after the j-loop)
    bf16x8 curH[4], curL[4];
    {
      const unsigned char* p_ = hW + (size_t)c * 8192 + laneoff;
      #pragma unroll
      for (int ot = 0; ot < 4; ++ot) {
        curH[ot] = *(const bf16x8*)(p_ + ot * 1024);
        curL[ot] = *(const bf16x8*)(p_ + ot * 1024 + 4096);
      }
    }
    // 1-ahead prefetch (unconditional: one-past reads stay inside d_ws)
    unsigned int w0n = bmr0[c + 1];
    unsigned int w1n = bmr1[c + 1];
    float4 evn0 = *(const float4*)(erp + (c + 1) * 32 + kg * 8);
    float4 evn1 = *(const float4*)(erp + (c + 1) * 32 + kg * 8 + 4);

    float ee[8] = {evc0.x, evc0.y, evc0.z, evc0.w,
                   evc1.x, evc1.y, evc1.z, evc1.w};

    bf16x8 af0h, af0l, af1h, af1l;
    #pragma unroll
    for (int j = 0; j < 8; ++j) {
      const int bitc = (j & 3) * 8 + (j >> 2);   // + 2*kg at runtime
      float e0 = eL0 + ee[j];
      e0 = fmaxf(e0, ALPHA * e0);
      float w0 = ((w0c >> (sh2 + bitc)) & 1u) ? __expf(e0) : 0.f;
      unsigned short h0 = f2bf(w0);
      float w0h = bf2f(h0);
      unsigned short l0 = f2bf(w0 - w0h);
      af0h[j] = (short)h0;
      af0l[j] = (short)l0;
      S0 += w0;                           // denom: <=2^-17 rel off numer

      float e1 = eL1 + ee[j];
      e1 = fmaxf(e1, ALPHA * e1);
      float w1 = ((w1c >> (sh2 + bitc)) & 1u) ? __expf(e1) : 0.f;
      unsigned short h1 = f2bf(w1);
      float w1h = bf2f(h1);
      unsigned short l1 = f2bf(w1 - w1h);
      af1h[j] = (short)h1;
      af1l[j] = (short)l1;
      S1 += w1;
    }

    #pragma unroll
    for (int ot = 0; ot < 4; ++ot) {
      acc[0][ot] = __builtin_amdgcn_mfma_f32_16x16x32_bf16(af0h, curH[ot], acc[0][ot], 0, 0, 0);
      acc[0][ot] = __builtin_amdgcn_mfma_f32_16x16x32_bf16(af0h, curL[ot], acc[0][ot], 0, 0, 0);
      acc[0][ot] = __builtin_amdgcn_mfma_f32_16x16x32_bf16(af0l, curH[ot], acc[0][ot], 0, 0, 0);
      acc[1][ot] = __builtin_amdgcn_mfma_f32_16x16x32_bf16(af1h, curH[ot], acc[1][ot], 0, 0, 0);
      acc[1][ot] = __builtin_amdgcn_mfma_f32_16x16x32_bf16(af1h, curL[ot], acc[1][ot], 0, 0, 0);
      acc[1][ot] = __builtin_amdgcn_mfma_f32_16x16x32_bf16(af1l, curH[ot], acc[1][ot], 0, 0, 0);
    }

    w0c = w0n; w1c = w1n; evc0 = evn0; evc1 = evn1;
  }

  // per-wave S reduce across kg groups (replicates row-l15 denom to all lanes)
  S0 += __shfl_xor(S0, 16); S0 += __shfl_xor(S0, 32);
  S1 += __shfl_xor(S1, 16); S1 += __shfl_xor(S1, 32);

  // cross-wave combine of m-window partials: waves 1..3 publish, wave 0 sums
  __syncthreads();
  if (wv > 0) {
    float* dst = cb + ((wv - 1) * 64 + l) * 36;
    #pragma unroll
    for (int ot = 0; ot < 4; ++ot) {
      *(f32x4*)(dst + ot * 4)      = acc[0][ot];
      *(f32x4*)(dst + 16 + ot * 4) = acc[1][ot];
    }
    dst[32] = S0;
    dst[33] = S1;
  }
  __syncthreads();
  if (wv != 0) return;

  #pragma unroll
  for (int p = 0; p < 3; ++p) {
    const float* src = cb + (p * 64 + l) * 36;
    #pragma unroll
    for (int ot = 0; ot < 4; ++ot) {
      acc[0][ot] += *(const f32x4*)(src + ot * 4);
      acc[1][ot] += *(const f32x4*)(src + 16 + ot * 4);
    }
    S0 += src[32];
    S1 += src[33];
  }

  float Sj0[4], Sj1[4];
  #pragma unroll
  for (int jj = 0; jj < 4; ++jj) {
    Sj0[jj] = __shfl(S0, kg * 4 + jj);
    Sj1[jj] = __shfl(S1, kg * 4 + jj);
  }
  #pragma unroll
  for (int ot = 0; ot < 4; ++ot) {
    #pragma unroll
    for (int jj = 0; jj < 4; ++jj) {
      float v0 = acc[0][ot][jj] / Sj0[jj];
      float r0 = v0 > 0.f ? v0 : expm1f(v0);
      out[((size_t)b * NN + n0 + kg * 4 + jj) * FOUT + ot * 16 + l15] = r0;
      float v1 = acc[1][ot][jj] / Sj1[jj];
      float r1 = v1 > 0.f ? v1 : expm1f(v1);
      out[((size_t)b * NN + n0 + 16 + kg * 4 + jj) * FOUT + ot * 16 + l15] = r1;
    }
  }
}

extern "C" void kernel_launch(void* const* d_in, const int* in_sizes, int n_in,
                              void* d_out, int out_size, void* d_ws, size_t ws_size,
                              hipStream_t stream) {
  const float* x   = (const float*)d_in[0];
  const int*   adj = (const int*)d_in[1];
  const float* W   = (const float*)d_in[2];
  const float* a   = (const float*)d_in[3];
  float* out = (float*)d_out;

  // ws layout: hS images (4MB) | el (64KB) | er (64KB) | bitmask (4MB)
  unsigned char* hS = (unsigned char*)d_ws;
  float* el = (float*)(hS + (size_t)BATCH * 32 * 16384);
  float* er = el + BATCH * NN;
  unsigned int* bm32 = (unsigned int*)(er + BATCH * NN);

  hipLaunchKernelGGL(k1_fused, dim3(1280), dim3(256), 0, stream,
                     x, adj, W, a, el, er, hS, bm32);
  hipLaunchKernelGGL(k2_attn, dim3(512), dim3(256), 0, stream,
                     bm32, hS, el, er, out);
}

// Round 13
// 50.921 us; speedup vs baseline: 5.2371x; 1.2483x over previous
//
#include <hip/hip_runtime.h>
#include <math.h>

#define BATCH 8
#define NN 2048
#define FIN 256
#define FOUT 64
#define ALPHA 0.2f

typedef __attribute__((ext_vector_type(8))) short bf16x8;
typedef __attribute__((ext_vector_type(4))) float f32x4;

static __device__ __forceinline__ unsigned short f2bf(float f) {
  unsigned int u = __float_as_uint(f);
  u += 0x7fffu + ((u >> 16) & 1u);
  return (unsigned short)(u >> 16);
}
static __device__ __forceinline__ float bf2f(unsigned short h) {
  return __uint_as_float(((unsigned int)h) << 16);
}
static __device__ __forceinline__ void gload16(const void* g, void* l) {
  __builtin_amdgcn_global_load_lds(
      (const __attribute__((address_space(1))) unsigned int*)g,
      (__attribute__((address_space(3))) unsigned int*)l, 16, 0, 0);
}

// ---------------------------------------------------------------------------
// K1: h = x@W via MFMA (hi/lo bf16 split), el/er via shuffle reduce, then
// emit per-64-row pre-swizzled h "staging images" for K2. (R7 version.)
// ---------------------------------------------------------------------------
__global__ __launch_bounds__(256) void k1_h(
    const float* __restrict__ x, const float* __restrict__ W,
    const float* __restrict__ a, float* __restrict__ el,
    float* __restrict__ er, unsigned char* __restrict__ hS) {
  __shared__ __align__(16) unsigned short lds[32768];  // 64 KB
  const int t = threadIdx.x;
  const int wv = t >> 6;
  const int l = t & 63;
  const int l15 = l & 15;
  const int kg = l >> 4;

  {
    const float4* W4 = (const float4*)W;
    #pragma unroll
    for (int i = 0; i < 16; ++i) {
      int f = t + i * 256;
      float4 v = W4[f];
      int k = f >> 4;
      int ob = (f & 15) * 4;
      float vv[4] = {v.x, v.y, v.z, v.w};
      #pragma unroll
      for (int c = 0; c < 4; ++c) {
        int o = ob + c;
        unsigned short hi = f2bf(vv[c]);
        unsigned short lo = f2bf(vv[c] - bf2f(hi));
        int idx = o * 256 + (((k >> 3) ^ (o & 7)) * 8) + (k & 7);
        lds[idx] = hi;
        lds[16384 + idx] = lo;
      }
    }
  }
  __syncthreads();

  const int row = blockIdx.x * 64 + wv * 16 + l15;
  f32x4 acc[4] = {{0.f,0.f,0.f,0.f},{0.f,0.f,0.f,0.f},
                  {0.f,0.f,0.f,0.f},{0.f,0.f,0.f,0.f}};
  const float* xrow = x + (size_t)row * FIN;

  #pragma unroll
  for (int ks = 0; ks < 8; ++ks) {
    int k0 = ks * 32;
    float4 xa = *(const float4*)(xrow + k0 + kg * 8);
    float4 xb = *(const float4*)(xrow + k0 + kg * 8 + 4);
    float xv[8] = {xa.x, xa.y, xa.z, xa.w, xb.x, xb.y, xb.z, xb.w};
    bf16x8 ahi, alo;
    #pragma unroll
    for (int j = 0; j < 8; ++j) {
      unsigned short hi = f2bf(xv[j]);
      unsigned short lo = f2bf(xv[j] - bf2f(hi));
      ahi[j] = (short)hi;
      alo[j] = (short)lo;
    }
    int kgidx = ks * 4 + kg;
    #pragma unroll
    for (int ot = 0; ot < 4; ++ot) {
      int o = ot * 16 + l15;
      int base = o * 256 + ((kgidx ^ (o & 7)) * 8);
      bf16x8 bhi = *(const bf16x8*)&lds[base];
      bf16x8 blo = *(const bf16x8*)&lds[16384 + base];
      acc[ot] = __builtin_amdgcn_mfma_f32_16x16x32_bf16(ahi, bhi, acc[ot], 0, 0, 0);
      acc[ot] = __builtin_amdgcn_mfma_f32_16x16x32_bf16(ahi, blo, acc[ot], 0, 0, 0);
      acc[ot] = __builtin_amdgcn_mfma_f32_16x16x32_bf16(alo, bhi, acc[ot], 0, 0, 0);
    }
  }

  float aLv[4], aRv[4];
  #pragma unroll
  for (int ot = 0; ot < 4; ++ot) {
    aLv[ot] = a[ot * 16 + l15];
    aRv[ot] = a[64 + ot * 16 + l15];
  }
  #pragma unroll
  for (int jj = 0; jj < 4; ++jj) {
    float pl = 0.f, pr = 0.f;
    #pragma unroll
    for (int ot = 0; ot < 4; ++ot) {
      pl += acc[ot][jj] * aLv[ot];
      pr += acc[ot][jj] * aRv[ot];
    }
    #pragma unroll
    for (int s = 1; s < 16; s <<= 1) {
      pl += __shfl_xor(pl, s);
      pr += __shfl_xor(pr, s);
    }
    if (l15 == 0) {
      int grow = blockIdx.x * 64 + wv * 16 + kg * 4 + jj;
      el[grow] = pl;
      er[grow] = pr;
    }
  }

  __syncthreads();
  #pragma unroll
  for (int ot = 0; ot < 4; ++ot) {
    int o = ot * 16 + l15;
    int xorv = (o >> 1) & 3;
    #pragma unroll
    for (int jj = 0; jj < 4; ++jj) {
      int m_loc = wv * 16 + kg * 4 + jj;
      int ks2 = m_loc >> 5;
      int kg2 = (m_loc >> 3) & 3;
      int j = m_loc & 7;
      int kgp = kg2 ^ xorv;
      float v = acc[ot][jj];
      unsigned short hi = f2bf(v);
      unsigned short lo = f2bf(v - bf2f(hi));
      int base = ((ks2 * 2 + 0) * 64 + o) * 32 + kgp * 8 + j;
      lds[base] = hi;
      lds[base + 2048] = lo;
    }
  }
  __syncthreads();

  {
    const uint4* src = (const uint4*)(const void*)lds;
    uint4* dst = (uint4*)(hS + (size_t)blockIdx.x * 16384);
    #pragma unroll
    for (int i = 0; i < 4; ++i) dst[t + i * 256] = src[t + i * 256];
  }
}

// ---------------------------------------------------------------------------
// K2: masked-softmax attention as MFMA GEMM — in-order-queue-aware pipeline.
// 512 blocks x 256 thr; block owns 32 n-rows, wave wv owns m-window
// [wv*512,(wv+1)*512) = 16 chunks of 32 m. Per-wave PRIVATE 2x8KB LDS dbuf.
// KEY: B-frags via global_load_lds (no dest VGPRs -> cannot be serialized by
// register reuse; consumed by ds_read on the lgkm queue, NOT vmem queue).
// Issue order per iter: STAGE(c+1)[8] -> er(c+2)[2] -> adj(c+3)[4]; then
// s_waitcnt vmcnt(N) where N = exactly the loads issued after S(c), so adj
// prefetches retire ~3 iterations (>900cyc) after issue with NO forced
// drain. N ladder: c=0:22, 1..12:20, 13:16, 14:10, 15:0. No loop barriers.
// Wide named slot arrays (av[4][4], ev[3][2]) force parallel load issue.
// ---------------------------------------------------------------------------
__global__ __launch_bounds__(256, 2) void k2_attn(
    const int* __restrict__ adj, const unsigned char* __restrict__ hS,
    const float* __restrict__ el, const float* __restrict__ er,
    float* __restrict__ out) {
  __shared__ __align__(1024) unsigned char buf[4][2][8192];  // 64 KB
  const int t = threadIdx.x;
  const int wv = t >> 6;
  const int l = t & 63;
  const int l15 = l & 15;
  const int kg = l >> 4;

  // XCD-bijective swizzle: 512 blocks, 64/XCD -> each XCD sees one batch
  int bid = blockIdx.x;
  int swz = (bid & 7) * 64 + (bid >> 3);
  int b = swz >> 6;
  int n0 = (swz & 63) * 32;

  const int row0 = n0 + l15;
  const int row1 = n0 + 16 + l15;
  const float eL0 = el[b * NN + row0];
  const float eL1 = el[b * NN + row1];
  const int* arow0 = adj + (size_t)b * NN * NN + (size_t)row0 * NN + wv * 512;
  const int* arow1 = adj + (size_t)b * NN * NN + (size_t)row1 * NN + wv * 512;
  const float* erp = er + b * NN + wv * 512;
  const unsigned char* hW = hS + (size_t)b * 32 * 16384 + (size_t)wv * 16 * 8192;
  const int laneoff = l15 * 64 + ((kg ^ ((l >> 1) & 3)) * 16);

  f32x4 acc[2][4] = {{{0.f,0.f,0.f,0.f},{0.f,0.f,0.f,0.f},
                      {0.f,0.f,0.f,0.f},{0.f,0.f,0.f,0.f}},
                     {{0.f,0.f,0.f,0.f},{0.f,0.f,0.f,0.f},
                      {0.f,0.f,0.f,0.f},{0.f,0.f,0.f,0.f}}};
  float S0 = 0.f, S1 = 0.f;

  int4 av[4][4];     // adj slots c..c+3 (3-ahead)
  float4 ev[3][2];   // er slots c..c+2 (2-ahead)

#define STAGE(cc) {                                                        \
    const unsigned char* src_ = hW + (size_t)(cc) * 8192;                  \
    unsigned char* dst_ = &buf[wv][(cc) & 1][0];                           \
    _Pragma("unroll")                                                      \
    for (int s_ = 0; s_ < 8; ++s_)                                         \
      gload16(src_ + s_ * 1024 + l * 16, dst_ + s_ * 1024);                \
  }
#define LOADE(slot, cc) {                                                  \
    int mb_ = (cc) * 32;                                                   \
    ev[slot][0] = *(const float4*)(erp + mb_ + kg * 8);                    \
    ev[slot][1] = *(const float4*)(erp + mb_ + kg * 8 + 4);                \
  }
#define LOADR(slot, cc) {                                                  \
    int mb_ = (cc) * 32;                                                   \
    av[slot][0] = *(const int4*)(arow0 + mb_ + kg * 8);                    \
    av[slot][1] = *(const int4*)(arow0 + mb_ + kg * 8 + 4);                \
    av[slot][2] = *(const int4*)(arow1 + mb_ + kg * 8);                    \
    av[slot][3] = *(const int4*)(arow1 + mb_ + kg * 8 + 4);                \
  }

  // prologue: S(0); E(0),E(1); R(0),R(1),R(2)
  STAGE(0);
  LOADE(0, 0); LOADE(1, 1);
  LOADR(0, 0); LOADR(1, 1); LOADR(2, 2);

  #pragma unroll
  for (int c = 0; c < 16; ++c) {
    if (c < 15) STAGE(c + 1);           // 8 gload_lds (no dest VGPRs)
    if (c < 14) LOADE((c + 2) % 3, c + 2);
    if (c < 13) LOADR((c + 3) & 3, c + 3);

    // wait for S(c)/E(c)/R(c) only; newer prefetches stay in flight
    if (c == 0)       { asm volatile("s_waitcnt vmcnt(22)" ::: "memory"); }
    else if (c <= 12) { asm volatile("s_waitcnt vmcnt(20)" ::: "memory"); }
    else if (c == 13) { asm volatile("s_waitcnt vmcnt(16)" ::: "memory"); }
    else if (c == 14) { asm volatile("s_waitcnt vmcnt(10)" ::: "memory"); }
    else              { asm volatile("s_waitcnt vmcnt(0)"  ::: "memory"); }
    __builtin_amdgcn_sched_barrier(0);

    const int sl = c & 3;
    const int se = c % 3;
    int a0[8] = {av[sl][0].x, av[sl][0].y, av[sl][0].z, av[sl][0].w,
                 av[sl][1].x, av[sl][1].y, av[sl][1].z, av[sl][1].w};
    int a1[8] = {av[sl][2].x, av[sl][2].y, av[sl][2].z, av[sl][2].w,
                 av[sl][3].x, av[sl][3].y, av[sl][3].z, av[sl][3].w};
    float ee[8] = {ev[se][0].x, ev[se][0].y, ev[se][0].z, ev[se][0].w,
                   ev[se][1].x, ev[se][1].y, ev[se][1].z, ev[se][1].w};

    bf16x8 af0h, af0l, af1h, af1l;
    #pragma unroll
    for (int j = 0; j < 8; ++j) {
      float e0 = eL0 + ee[j];
      e0 = fmaxf(e0, ALPHA * e0);
      float w0 = (a0[j] > 0) ? __expf(e0) : 0.f;
      unsigned short h0 = f2bf(w0);
      float w0h = bf2f(h0);
      unsigned short l0 = f2bf(w0 - w0h);
      af0h[j] = (short)h0;
      af0l[j] = (short)l0;
      S0 += w0;

      float e1 = eL1 + ee[j];
      e1 = fmaxf(e1, ALPHA * e1);
      float w1 = (a1[j] > 0) ? __expf(e1) : 0.f;
      unsigned short h1 = f2bf(w1);
      float w1h = bf2f(h1);
      unsigned short l1 = f2bf(w1 - w1h);
      af1h[j] = (short)h1;
      af1l[j] = (short)l1;
      S1 += w1;
    }

    const unsigned char* cur = &buf[wv][c & 1][0];
    #pragma unroll
    for (int ot = 0; ot < 4; ++ot) {
      const unsigned char* p = cur + ot * 1024 + laneoff;
      bf16x8 bhi = *(const bf16x8*)p;          // ds_read_b128 (lgkm queue)
      bf16x8 blo = *(const bf16x8*)(p + 4096);
      acc[0][ot] = __builtin_amdgcn_mfma_f32_16x16x32_bf16(af0h, bhi, acc[0][ot], 0, 0, 0);
      acc[0][ot] = __builtin_amdgcn_mfma_f32_16x16x32_bf16(af0h, blo, acc[0][ot], 0, 0, 0);
      acc[0][ot] = __builtin_amdgcn_mfma_f32_16x16x32_bf16(af0l, bhi, acc[0][ot], 0, 0, 0);
      acc[1][ot] = __builtin_amdgcn_mfma_f32_16x16x32_bf16(af1h, bhi, acc[1][ot], 0, 0, 0);
      acc[1][ot] = __builtin_amdgcn_mfma_f32_16x16x32_bf16(af1h, blo, acc[1][ot], 0, 0, 0);
      acc[1][ot] = __builtin_amdgcn_mfma_f32_16x16x32_bf16(af1l, bhi, acc[1][ot], 0, 0, 0);
    }
  }
#undef STAGE
#undef LOADE
#undef LOADR

  // per-wave S reduce across kg groups
  S0 += __shfl_xor(S0, 16); S0 += __shfl_xor(S0, 32);
  S1 += __shfl_xor(S1, 16); S1 += __shfl_xor(S1, 32);

  // cross-wave combine of m-window partials (reuse buf as f32 scratch)
  __syncthreads();
  float* cb = (float*)(void*)&buf[0][0][0];
  if (wv > 0) {
    float* dst = cb + ((wv - 1) * 64 + l) * 36;
    #pragma unroll
    for (int ot = 0; ot < 4; ++ot) {
      *(f32x4*)(dst + ot * 4)      = acc[0][ot];
      *(f32x4*)(dst + 16 + ot * 4) = acc[1][ot];
    }
    dst[32] = S0;
    dst[33] = S1;
  }
  __syncthreads();
  if (wv != 0) return;

  #pragma unroll
  for (int p = 0; p < 3; ++p) {
    const float* src = cb + (p * 64 + l) * 36;
    #pragma unroll
    for (int ot = 0; ot < 4; ++ot) {
      acc[0][ot] += *(const f32x4*)(src + ot * 4);
      acc[1][ot] += *(const f32x4*)(src + 16 + ot * 4);
    }
    S0 += src[32];
    S1 += src[33];
  }

  float Sj0[4], Sj1[4];
  #pragma unroll
  for (int jj = 0; jj < 4; ++jj) {
    Sj0[jj] = __shfl(S0, kg * 4 + jj);
    Sj1[jj] = __shfl(S1, kg * 4 + jj);
  }
  #pragma unroll
  for (int ot = 0; ot < 4; ++ot) {
    #pragma unroll
    for (int jj = 0; jj < 4; ++jj) {
      float v0 = acc[0][ot][jj] / Sj0[jj];
      float r0 = v0 > 0.f ? v0 : expm1f(v0);
      out[((size_t)b * NN + n0 + kg * 4 + jj) * FOUT + ot * 16 + l15] = r0;
      float v1 = acc[1][ot][jj] / Sj1[jj];
      float r1 = v1 > 0.f ? v1 : expm1f(v1);
      out[((size_t)b * NN + n0 + 16 + kg * 4 + jj) * FOUT + ot * 16 + l15] = r1;
    }
  }
}

extern "C" void kernel_launch(void* const* d_in, const int* in_sizes, int n_in,
                              void* d_out, int out_size, void* d_ws, size_t ws_size,
                              hipStream_t stream) {
  const float* x   = (const float*)d_in[0];
  const int*   adj = (const int*)d_in[1];
  const float* W   = (const float*)d_in[2];
  const float* a   = (const float*)d_in[3];
  float* out = (float*)d_out;

  // ws layout: hS images (4MB) | el (64KB) | er (64KB)
  unsigned char* hS = (unsigned char*)d_ws;
  float* el = (float*)(hS + (size_t)BATCH * 32 * 16384);
  float* er = el + BATCH * NN;

  hipLaunchKernelGGL(k1_h, dim3(256), dim3(256), 0, stream, x, W, a, el, er, hS);
  hipLaunchKernelGGL(k2_attn, dim3(512), dim3(256), 0, stream, adj, hS, el, er, out);
}